// Round 1
// baseline (615.235 us; speedup 1.0000x reference)
//
#include <hip/hip_runtime.h>

// GCN: 3 layers, N=50000 nodes, E=800000 edges, fp32.
// Pipeline per call:
//   1. degree count (int atomics) -> block scan -> CSR offsets -> fill esrc
//   2. per layer: SGEMM (x@W+b)*snorm -> H ; gather over CSR: relu(sum*rnorm) -> X/out

static __device__ __forceinline__ float reluf(float x){ return x > 0.f ? x : 0.f; }

__global__ void count_kernel(const int* __restrict__ snd, const int* __restrict__ rcv,
                             int* __restrict__ scnt, int* __restrict__ rcnt, int e)
{
    int i = blockIdx.x * blockDim.x + threadIdx.x;
    if (i < e) {
        atomicAdd(&scnt[snd[i]], 1);
        atomicAdd(&rcnt[rcv[i]], 1);
    }
}

__global__ void scan_block_kernel(const int* __restrict__ cnt, int* __restrict__ tmp,
                                  int* __restrict__ bsum, int n)
{
    __shared__ int s[1024];
    int i = blockIdx.x * 1024 + threadIdx.x;
    int v = (i < n) ? cnt[i] : 0;
    s[threadIdx.x] = v;
    __syncthreads();
    for (int d = 1; d < 1024; d <<= 1) {
        int t = (threadIdx.x >= (unsigned)d) ? s[threadIdx.x - d] : 0;
        __syncthreads();
        s[threadIdx.x] += t;
        __syncthreads();
    }
    if (i < n) tmp[i] = s[threadIdx.x];
    if (threadIdx.x == 1023) bsum[blockIdx.x] = s[1023];
}

__global__ void scan_tops_kernel(int* bsum, int nb)
{
    __shared__ int s[64];
    int v = ((int)threadIdx.x < nb) ? bsum[threadIdx.x] : 0;
    s[threadIdx.x] = v;
    __syncthreads();
    for (int d = 1; d < 64; d <<= 1) {
        int t = (threadIdx.x >= (unsigned)d) ? s[threadIdx.x - d] : 0;
        __syncthreads();
        s[threadIdx.x] += t;
        __syncthreads();
    }
    if ((int)threadIdx.x < nb) bsum[threadIdx.x] = s[threadIdx.x] - v;  // exclusive
}

__global__ void finalize_kernel(const int* __restrict__ tmp, const int* __restrict__ bsum,
                                const int* __restrict__ rcnt, const int* __restrict__ scnt,
                                int* __restrict__ off, float* __restrict__ rnorm,
                                float* __restrict__ snorm, int n)
{
    int i = blockIdx.x * blockDim.x + threadIdx.x;
    if (i >= n) return;
    off[i + 1] = tmp[i] + bsum[i >> 10];
    if (i == 0) off[0] = 0;
    rnorm[i] = rsqrtf(fmaxf((float)rcnt[i], 1.0f));
    snorm[i] = rsqrtf(fmaxf((float)scnt[i], 1.0f));
}

__global__ void fill_kernel(const int* __restrict__ snd, const int* __restrict__ rcv,
                            const int* __restrict__ off, int* __restrict__ cursor,
                            int* __restrict__ esrc, int e)
{
    int i = blockIdx.x * blockDim.x + threadIdx.x;
    if (i < e) {
        int r = rcv[i];
        int p = off[r] + atomicAdd(&cursor[r], 1);
        esrc[p] = snd[i];
    }
}

// SGEMM: H[row][col] = (sum_k X[row][k]*W[k][col] + bias[col]) * snorm[row]
// 64 rows x NOUT cols per 256-thread block; K staged in chunks of 32.
template<int K, int NOUT>
__global__ __launch_bounds__(256)
void gemm_kernel(const float* __restrict__ X, const float* __restrict__ W,
                 const float* __restrict__ bias, const float* __restrict__ snorm,
                 float* __restrict__ H, int n)
{
    constexpr int BM = 64, KT = 32;
    constexpr int NB = NOUT / 64;           // float4 col-groups per thread (4 or 2)
    __shared__ float Xs[KT][BM + 4];        // transposed [k][row], stride 68 (b128-aligned, padded)
    __shared__ float Ws[KT][NOUT];
    const int tid = threadIdx.x;
    const int tx = tid & 15;                // 16 col-groups
    const int ty = tid >> 4;                // 16 row-groups of 4 rows
    const int r0 = blockIdx.x * BM;

    float acc[4][NB * 4];
#pragma unroll
    for (int i = 0; i < 4; ++i)
#pragma unroll
        for (int j = 0; j < NB * 4; ++j) acc[i][j] = 0.f;

    for (int k0 = 0; k0 < K; k0 += KT) {
        // stage X tile (64 x 32) transposed: 512 float4, 2 per thread
#pragma unroll
        for (int t = 0; t < 2; ++t) {
            int idx = tid + t * 256;
            int row = idx >> 3, kv = idx & 7;
            int gr = r0 + row; if (gr > n - 1) gr = n - 1;
            float4 v = *(const float4*)(X + (size_t)gr * K + k0 + kv * 4);
            Xs[kv * 4 + 0][row] = v.x;
            Xs[kv * 4 + 1][row] = v.y;
            Xs[kv * 4 + 2][row] = v.z;
            Xs[kv * 4 + 3][row] = v.w;
        }
        // stage W chunk (32 x NOUT)
#pragma unroll
        for (int t = 0; t < KT * NOUT / 1024; ++t) {
            int idx = tid + t * 256;
            int kk = idx / (NOUT / 4), c4 = idx % (NOUT / 4);
            *(float4*)&Ws[kk][c4 * 4] = *(const float4*)(W + (size_t)(k0 + kk) * NOUT + c4 * 4);
        }
        __syncthreads();
#pragma unroll
        for (int kk = 0; kk < KT; ++kk) {
            float4 a = *(const float4*)&Xs[kk][ty * 4];
            float av[4] = { a.x, a.y, a.z, a.w };
#pragma unroll
            for (int j = 0; j < NB; ++j) {
                float4 b = *(const float4*)&Ws[kk][j * 64 + tx * 4];
#pragma unroll
                for (int i = 0; i < 4; ++i) {
                    acc[i][j * 4 + 0] += av[i] * b.x;
                    acc[i][j * 4 + 1] += av[i] * b.y;
                    acc[i][j * 4 + 2] += av[i] * b.z;
                    acc[i][j * 4 + 3] += av[i] * b.w;
                }
            }
        }
        __syncthreads();
    }
#pragma unroll
    for (int i = 0; i < 4; ++i) {
        int row = r0 + ty * 4 + i;
        if (row < n) {
            float s = snorm[row];
#pragma unroll
            for (int j = 0; j < NB; ++j) {
                int col = j * 64 + tx * 4;
                float4 bb = *(const float4*)(bias + col);
                float4 o;
                o.x = (acc[i][j * 4 + 0] + bb.x) * s;
                o.y = (acc[i][j * 4 + 1] + bb.y) * s;
                o.z = (acc[i][j * 4 + 2] + bb.z) * s;
                o.w = (acc[i][j * 4 + 3] + bb.w) * s;
                *(float4*)(H + (size_t)row * NOUT + col) = o;
            }
        }
    }
}

// Per receiver node: sum incoming H rows (CSR), scale by rnorm, relu, store.
template<int F>
__global__ __launch_bounds__(256)
void gather_kernel(const float* __restrict__ H, const int* __restrict__ off,
                   const int* __restrict__ esrc, const float* __restrict__ rnorm,
                   float* __restrict__ out, int n)
{
    constexpr int LPN = F / 4;              // lanes per node (64 or 32)
    int g = blockIdx.x * 256 + threadIdx.x;
    int node = g / LPN;
    int lane = g % LPN;
    if (node >= n) return;
    int e0 = off[node], e1 = off[node + 1];
    float ax = 0.f, ay = 0.f, az = 0.f, aw = 0.f;
    for (int e = e0; e < e1; ++e) {
        int s = esrc[e];
        float4 v = *(const float4*)(H + (size_t)s * F + lane * 4);
        ax += v.x; ay += v.y; az += v.z; aw += v.w;
    }
    float rn = rnorm[node];
    float4 o = { reluf(ax * rn), reluf(ay * rn), reluf(az * rn), reluf(aw * rn) };
    *(float4*)(out + (size_t)node * F + lane * 4) = o;
}

extern "C" void kernel_launch(void* const* d_in, const int* in_sizes, int n_in,
                              void* d_out, int out_size, void* d_ws, size_t ws_size,
                              hipStream_t stream)
{
    const float* nodes = (const float*)d_in[0];
    const int*   snd   = (const int*)d_in[1];
    const int*   rcv   = (const int*)d_in[2];
    const float* W1    = (const float*)d_in[3];
    const float* b1    = (const float*)d_in[4];
    const float* W2    = (const float*)d_in[5];
    const float* b2    = (const float*)d_in[6];
    const float* W3    = (const float*)d_in[7];
    const float* b3    = (const float*)d_in[8];
    const int n = in_sizes[0] / 128;
    const int e = in_sizes[1];
    float* out = (float*)d_out;

    char* w = (char*)d_ws;
    size_t o = 0;
    auto alloc = [&](size_t b){ size_t p = o; o += (b + 255) & ~(size_t)255; return p; };
    float* H     = (float*)(w + alloc((size_t)n * 256 * 4));
    float* Xb    = (float*)(w + alloc((size_t)n * 256 * 4));
    int*   scnt  = (int*)  (w + alloc((size_t)n * 4 * 3));   // scnt, rcnt, cursor contiguous
    int*   rcnt  = scnt + n;
    int*   cursor= scnt + 2 * n;
    int*   tmp   = (int*)  (w + alloc((size_t)n * 4));
    int*   off   = (int*)  (w + alloc((size_t)(n + 1) * 4));
    int*   bsum  = (int*)  (w + alloc(64 * 4));
    int*   esrc  = (int*)  (w + alloc((size_t)e * 4));
    float* snorm = (float*)(w + alloc((size_t)n * 4));
    float* rnorm = (float*)(w + alloc((size_t)n * 4));

    hipMemsetAsync(scnt, 0, (size_t)n * 4 * 3, stream);

    int eb = (e + 255) / 256;
    count_kernel<<<eb, 256, 0, stream>>>(snd, rcv, scnt, rcnt, e);
    int nb = (n + 1023) / 1024;
    scan_block_kernel<<<nb, 1024, 0, stream>>>(rcnt, tmp, bsum, n);
    scan_tops_kernel<<<1, 64, 0, stream>>>(bsum, nb);
    finalize_kernel<<<(n + 255) / 256, 256, 0, stream>>>(tmp, bsum, rcnt, scnt, off, rnorm, snorm, n);
    fill_kernel<<<eb, 256, 0, stream>>>(snd, rcv, off, cursor, esrc, e);

    int gb = (n + 63) / 64;
    gemm_kernel<128, 256><<<gb, 256, 0, stream>>>(nodes, W1, b1, snorm, H, n);
    gather_kernel<256><<<(n * 64 + 255) / 256, 256, 0, stream>>>(H, off, esrc, rnorm, Xb, n);
    gemm_kernel<256, 256><<<gb, 256, 0, stream>>>(Xb, W2, b2, snorm, H, n);
    gather_kernel<256><<<(n * 64 + 255) / 256, 256, 0, stream>>>(H, off, esrc, rnorm, Xb, n);
    gemm_kernel<256, 128><<<gb, 256, 0, stream>>>(Xb, W3, b3, snorm, H, n);
    gather_kernel<128><<<(n * 32 + 255) / 256, 256, 0, stream>>>(H, off, esrc, rnorm, out, n);
}

// Round 2
// 452.435 us; speedup vs baseline: 1.3598x; 1.3598x over previous
//
#include <hip/hip_runtime.h>

// GCN 3-layer, N=50000, E=800000, fp32 in/out.
// Pipeline:
//   CSR build (count -> scan -> fill)
//   L1: gather(nodes*snorm, +sum snorm) -> bf16 split G ; MFMA-GEMM 128->256 (bf16x3) epilogue relu((acc)*rnorm + b*gs*rnorm) -> bf16 split X2
//   L2: MFMA-GEMM 256->256 epilogue (acc+b)*snorm -> fp32 H ; gather -> relu(*rnorm) -> bf16 split X3
//   L3: MFMA-GEMM 256->128 epilogue (acc+b)*snorm -> fp32 H ; gather -> relu(*rnorm) -> out

typedef __attribute__((ext_vector_type(8))) short short8;
typedef __attribute__((ext_vector_type(4))) float f32x4;

static __device__ __forceinline__ float reluf(float x){ return x > 0.f ? x : 0.f; }

static __device__ __forceinline__ unsigned short bf16_rn(float v){
    unsigned u = __float_as_uint(v);
    unsigned r = u + 0x7FFFu + ((u >> 16) & 1u);
    return (unsigned short)(r >> 16);
}
static __device__ __forceinline__ void split2(float v, unsigned short& h, unsigned short& l){
    unsigned short hh = bf16_rn(v);
    float hf = __uint_as_float(((unsigned)hh) << 16);
    h = hh;
    l = bf16_rn(v - hf);
}

static __device__ __forceinline__ void gload_lds16(const void* g, void* lds){
    __builtin_amdgcn_global_load_lds((const __attribute__((address_space(1))) unsigned int*)g,
                                     (__attribute__((address_space(3))) unsigned int*)lds, 16, 0, 0);
}

// ---------------- preprocessing (CSR build) ----------------

__global__ void count_kernel(const int* __restrict__ snd, const int* __restrict__ rcv,
                             int* __restrict__ scnt, int* __restrict__ rcnt, int e)
{
    int i = blockIdx.x * blockDim.x + threadIdx.x;
    if (i < e) {
        atomicAdd(&scnt[snd[i]], 1);
        atomicAdd(&rcnt[rcv[i]], 1);
    }
}

__global__ void scan_block_kernel(const int* __restrict__ cnt, int* __restrict__ tmp,
                                  int* __restrict__ bsum, int n)
{
    __shared__ int s[1024];
    int i = blockIdx.x * 1024 + threadIdx.x;
    int v = (i < n) ? cnt[i] : 0;
    s[threadIdx.x] = v;
    __syncthreads();
    for (int d = 1; d < 1024; d <<= 1) {
        int t = (threadIdx.x >= (unsigned)d) ? s[threadIdx.x - d] : 0;
        __syncthreads();
        s[threadIdx.x] += t;
        __syncthreads();
    }
    if (i < n) tmp[i] = s[threadIdx.x];
    if (threadIdx.x == 1023) bsum[blockIdx.x] = s[1023];
}

__global__ void scan_tops_kernel(int* bsum, int nb)
{
    __shared__ int s[64];
    int v = ((int)threadIdx.x < nb) ? bsum[threadIdx.x] : 0;
    s[threadIdx.x] = v;
    __syncthreads();
    for (int d = 1; d < 64; d <<= 1) {
        int t = (threadIdx.x >= (unsigned)d) ? s[threadIdx.x - d] : 0;
        __syncthreads();
        s[threadIdx.x] += t;
        __syncthreads();
    }
    if ((int)threadIdx.x < nb) bsum[threadIdx.x] = s[threadIdx.x] - v;  // exclusive
}

__global__ void finalize_kernel(const int* __restrict__ tmp, const int* __restrict__ bsum,
                                const int* __restrict__ rcnt, const int* __restrict__ scnt,
                                int* __restrict__ off, float* __restrict__ rnorm,
                                float* __restrict__ snorm, int n)
{
    int i = blockIdx.x * blockDim.x + threadIdx.x;
    if (i >= n) return;
    off[i + 1] = tmp[i] + bsum[i >> 10];
    if (i == 0) off[0] = 0;
    rnorm[i] = rsqrtf(fmaxf((float)rcnt[i], 1.0f));
    snorm[i] = rsqrtf(fmaxf((float)scnt[i], 1.0f));
}

__global__ void fill_kernel(const int* __restrict__ snd, const int* __restrict__ rcv,
                            const int* __restrict__ off, int* __restrict__ cursor,
                            int* __restrict__ esrc, int e)
{
    int i = blockIdx.x * blockDim.x + threadIdx.x;
    if (i < e) {
        int r = rcv[i];
        int p = off[r] + atomicAdd(&cursor[r], 1);
        esrc[p] = snd[i];
    }
}

// ---------------- weight split + transpose ----------------
// W [K][N] fp32 -> Th/Tl [N][K] bf16 (hi/lo split)
__global__ void wsplit_kernel(const float* __restrict__ W, unsigned short* __restrict__ Th,
                              unsigned short* __restrict__ Tl, int K, int N)
{
    int i = blockIdx.x * 256 + threadIdx.x;
    if (i >= K * N) return;
    int k = i / N, c = i % N;
    unsigned short h, l;
    split2(W[i], h, l);
    Th[c * K + k] = h;
    Tl[c * K + k] = l;
}

// ---------------- MFMA GEMM (bf16x3 split fp32 emulation) ----------------
// C[r][c] = sum_k A[r][k]*B[k][c] with A = Ah+Al (bf16 pair, [n][K] row-major),
// B given transposed as Wt = Bh+Bl ([NOUT][K] row-major).
// epilogue: v = acc*rs[r] + bias[c]*bs[r]; RELU_SPLIT ? write relu(v) as bf16 pair : write fp32.
template<int K, int NOUT, bool RELU_SPLIT>
__global__ __launch_bounds__(256)
void mfma_gemm(const unsigned short* __restrict__ Ah_g, const unsigned short* __restrict__ Al_g,
               const unsigned short* __restrict__ Bh_g, const unsigned short* __restrict__ Bl_g,
               const float* __restrict__ bias, const float* __restrict__ rs,
               const float* __restrict__ bs, float* __restrict__ Hout,
               unsigned short* __restrict__ Oh, unsigned short* __restrict__ Ol, int n)
{
    __shared__ unsigned short smem[4 * 128 * 32];
    unsigned short* Ah = smem;
    unsigned short* Al = smem + 4096;
    unsigned short* Bh = smem + 8192;
    unsigned short* Bl = smem + 12288;

    const int tid = threadIdx.x;
    const int wid = tid >> 6, lane = tid & 63;
    const int wr = (wid >> 1) * 64, wc = (wid & 1) * 64;
    const int r0 = blockIdx.x * 128, c0 = blockIdx.y * 128;

    f32x4 acc[4][4];
#pragma unroll
    for (int m = 0; m < 4; ++m)
#pragma unroll
        for (int q = 0; q < 4; ++q) acc[m][q] = (f32x4){0.f, 0.f, 0.f, 0.f};

    const int ks = lane >> 4, lr = lane & 15;

    for (int k0 = 0; k0 < K; k0 += 32) {
        // stage 4 x (128 rows x 32 k) bf16 tiles; LDS linear, XOR-swizzle applied on
        // the GLOBAL k-group so that reads at slot = ks ^ ((row>>1)&3) are 2-way max.
#pragma unroll
        for (int c = 0; c < 2; ++c) {
            int i = tid + c * 256;
            int row = i >> 2, p = i & 3;
            int g = p ^ ((row >> 1) & 3);
            int ar = r0 + row; if (ar >= n) ar = n - 1;
            size_t aoff = (size_t)ar * K + k0 + g * 8;
            size_t boff = (size_t)(c0 + row) * K + k0 + g * 8;
            gload_lds16(Ah_g + aoff, Ah + i * 8);
            gload_lds16(Al_g + aoff, Al + i * 8);
            gload_lds16(Bh_g + boff, Bh + i * 8);
            gload_lds16(Bl_g + boff, Bl + i * 8);
        }
        __syncthreads();

        short8 a_h[4], a_l[4], b_h[4], b_l[4];
#pragma unroll
        for (int m = 0; m < 4; ++m) {
            int r = wr + m * 16 + lr;
            int slot = ks ^ ((r >> 1) & 3);
            a_h[m] = *(const short8*)(Ah + r * 32 + slot * 8);
            a_l[m] = *(const short8*)(Al + r * 32 + slot * 8);
        }
#pragma unroll
        for (int q = 0; q < 4; ++q) {
            int r = wc + q * 16 + lr;
            int slot = ks ^ ((r >> 1) & 3);
            b_h[q] = *(const short8*)(Bh + r * 32 + slot * 8);
            b_l[q] = *(const short8*)(Bl + r * 32 + slot * 8);
        }
#pragma unroll
        for (int m = 0; m < 4; ++m)
#pragma unroll
            for (int q = 0; q < 4; ++q) {
                acc[m][q] = __builtin_amdgcn_mfma_f32_16x16x32_bf16(a_h[m], b_h[q], acc[m][q], 0, 0, 0);
                acc[m][q] = __builtin_amdgcn_mfma_f32_16x16x32_bf16(a_h[m], b_l[q], acc[m][q], 0, 0, 0);
                acc[m][q] = __builtin_amdgcn_mfma_f32_16x16x32_bf16(a_l[m], b_h[q], acc[m][q], 0, 0, 0);
            }
        __syncthreads();
    }

    // epilogue: C/D layout (verified): col = lane&15, row = (lane>>4)*4 + reg
    const int lq = lane >> 4;
#pragma unroll
    for (int m = 0; m < 4; ++m) {
#pragma unroll
        for (int j = 0; j < 4; ++j) {
            int r = r0 + wr + m * 16 + lq * 4 + j;
            if (r < n) {
                float rsv = rs[r], bsv = bs[r];
#pragma unroll
                for (int q = 0; q < 4; ++q) {
                    int cg = c0 + wc + q * 16 + lr;
                    float v = acc[m][q][j] * rsv + bias[cg] * bsv;
                    if (RELU_SPLIT) {
                        v = reluf(v);
                        unsigned short h, l;
                        split2(v, h, l);
                        Oh[(size_t)r * NOUT + cg] = h;
                        Ol[(size_t)r * NOUT + cg] = l;
                    } else {
                        Hout[(size_t)r * NOUT + cg] = v;
                    }
                }
            }
        }
    }
}

// ---------------- gathers ----------------
// L1: G[i] = sum_{s in in(i)} nodes[s]*snorm[s]; bs[i] = (sum snorm[s]) * rnorm[i]
// write G as bf16 pair. F=128, 32 lanes/node.
__global__ __launch_bounds__(256)
void gather1_kernel(const float* __restrict__ nodes, const int* __restrict__ off,
                    const int* __restrict__ esrc, const float* __restrict__ snorm,
                    const float* __restrict__ rnorm,
                    unsigned short* __restrict__ Gh, unsigned short* __restrict__ Gl,
                    float* __restrict__ bs, int n)
{
    int g = blockIdx.x * 256 + threadIdx.x;
    int node = g >> 5, lane = g & 31;
    if (node >= n) return;
    int e0 = off[node], e1 = off[node + 1];
    float ax = 0, ay = 0, az = 0, aw = 0, gs = 0;
    int e = e0;
    for (; e + 4 <= e1; e += 4) {
        int s0 = esrc[e], s1 = esrc[e + 1], s2 = esrc[e + 2], s3 = esrc[e + 3];
        float n0 = snorm[s0], n1 = snorm[s1], n2 = snorm[s2], n3 = snorm[s3];
        float4 v0 = *(const float4*)(nodes + (size_t)s0 * 128 + lane * 4);
        float4 v1 = *(const float4*)(nodes + (size_t)s1 * 128 + lane * 4);
        float4 v2 = *(const float4*)(nodes + (size_t)s2 * 128 + lane * 4);
        float4 v3 = *(const float4*)(nodes + (size_t)s3 * 128 + lane * 4);
        ax += v0.x * n0 + v1.x * n1 + v2.x * n2 + v3.x * n3;
        ay += v0.y * n0 + v1.y * n1 + v2.y * n2 + v3.y * n3;
        az += v0.z * n0 + v1.z * n1 + v2.z * n2 + v3.z * n3;
        aw += v0.w * n0 + v1.w * n1 + v2.w * n2 + v3.w * n3;
        gs += n0 + n1 + n2 + n3;
    }
    for (; e < e1; ++e) {
        int s = esrc[e];
        float ns = snorm[s];
        float4 v = *(const float4*)(nodes + (size_t)s * 128 + lane * 4);
        ax += v.x * ns; ay += v.y * ns; az += v.z * ns; aw += v.w * ns;
        gs += ns;
    }
    float vv[4] = { ax, ay, az, aw };
    unsigned short h[4], l[4];
#pragma unroll
    for (int i = 0; i < 4; ++i) split2(vv[i], h[i], l[i]);
    size_t o = (size_t)node * 128 + lane * 4;
    *(ushort4*)(Gh + o) = make_ushort4(h[0], h[1], h[2], h[3]);
    *(ushort4*)(Gl + o) = make_ushort4(l[0], l[1], l[2], l[3]);
    if (lane == 0) bs[node] = gs * rnorm[node];
}

// L2: X3[i] = relu(rnorm[i] * sum H[s]); F=256, 64 lanes/node, bf16-pair out.
__global__ __launch_bounds__(256)
void gather2_kernel(const float* __restrict__ H, const int* __restrict__ off,
                    const int* __restrict__ esrc, const float* __restrict__ rnorm,
                    unsigned short* __restrict__ Oh, unsigned short* __restrict__ Ol, int n)
{
    int g = blockIdx.x * 256 + threadIdx.x;
    int node = g >> 6, lane = g & 63;
    if (node >= n) return;
    int e0 = off[node], e1 = off[node + 1];
    float ax = 0, ay = 0, az = 0, aw = 0;
    int e = e0;
    for (; e + 4 <= e1; e += 4) {
        int s0 = esrc[e], s1 = esrc[e + 1], s2 = esrc[e + 2], s3 = esrc[e + 3];
        float4 v0 = *(const float4*)(H + (size_t)s0 * 256 + lane * 4);
        float4 v1 = *(const float4*)(H + (size_t)s1 * 256 + lane * 4);
        float4 v2 = *(const float4*)(H + (size_t)s2 * 256 + lane * 4);
        float4 v3 = *(const float4*)(H + (size_t)s3 * 256 + lane * 4);
        ax += v0.x + v1.x + v2.x + v3.x;
        ay += v0.y + v1.y + v2.y + v3.y;
        az += v0.z + v1.z + v2.z + v3.z;
        aw += v0.w + v1.w + v2.w + v3.w;
    }
    for (; e < e1; ++e) {
        int s = esrc[e];
        float4 v = *(const float4*)(H + (size_t)s * 256 + lane * 4);
        ax += v.x; ay += v.y; az += v.z; aw += v.w;
    }
    float rn = rnorm[node];
    float vv[4] = { reluf(ax * rn), reluf(ay * rn), reluf(az * rn), reluf(aw * rn) };
    unsigned short h[4], l[4];
#pragma unroll
    for (int i = 0; i < 4; ++i) split2(vv[i], h[i], l[i]);
    size_t o = (size_t)node * 256 + lane * 4;
    *(ushort4*)(Oh + o) = make_ushort4(h[0], h[1], h[2], h[3]);
    *(ushort4*)(Ol + o) = make_ushort4(l[0], l[1], l[2], l[3]);
}

// L3: out[i] = relu(rnorm[i] * sum H[s]); F=128, fp32 out.
__global__ __launch_bounds__(256)
void gather3_kernel(const float* __restrict__ H, const int* __restrict__ off,
                    const int* __restrict__ esrc, const float* __restrict__ rnorm,
                    float* __restrict__ out, int n)
{
    int g = blockIdx.x * 256 + threadIdx.x;
    int node = g >> 5, lane = g & 31;
    if (node >= n) return;
    int e0 = off[node], e1 = off[node + 1];
    float ax = 0, ay = 0, az = 0, aw = 0;
    int e = e0;
    for (; e + 4 <= e1; e += 4) {
        int s0 = esrc[e], s1 = esrc[e + 1], s2 = esrc[e + 2], s3 = esrc[e + 3];
        float4 v0 = *(const float4*)(H + (size_t)s0 * 128 + lane * 4);
        float4 v1 = *(const float4*)(H + (size_t)s1 * 128 + lane * 4);
        float4 v2 = *(const float4*)(H + (size_t)s2 * 128 + lane * 4);
        float4 v3 = *(const float4*)(H + (size_t)s3 * 128 + lane * 4);
        ax += v0.x + v1.x + v2.x + v3.x;
        ay += v0.y + v1.y + v2.y + v3.y;
        az += v0.z + v1.z + v2.z + v3.z;
        aw += v0.w + v1.w + v2.w + v3.w;
    }
    for (; e < e1; ++e) {
        int s = esrc[e];
        float4 v = *(const float4*)(H + (size_t)s * 128 + lane * 4);
        ax += v.x; ay += v.y; az += v.z; aw += v.w;
    }
    float rn = rnorm[node];
    float4 o = { reluf(ax * rn), reluf(ay * rn), reluf(az * rn), reluf(aw * rn) };
    *(float4*)(out + (size_t)node * 128 + lane * 4) = o;
}

// ---------------- launch ----------------

extern "C" void kernel_launch(void* const* d_in, const int* in_sizes, int n_in,
                              void* d_out, int out_size, void* d_ws, size_t ws_size,
                              hipStream_t stream)
{
    const float* nodes = (const float*)d_in[0];
    const int*   snd   = (const int*)d_in[1];
    const int*   rcv   = (const int*)d_in[2];
    const float* W1    = (const float*)d_in[3];
    const float* b1    = (const float*)d_in[4];
    const float* W2    = (const float*)d_in[5];
    const float* b2    = (const float*)d_in[6];
    const float* W3    = (const float*)d_in[7];
    const float* b3    = (const float*)d_in[8];
    const int n = in_sizes[0] / 128;
    const int e = in_sizes[1];
    float* out = (float*)d_out;

    char* w = (char*)d_ws;
    size_t o = 0;
    auto alloc = [&](size_t b){ size_t p = o; o += (b + 255) & ~(size_t)255; return p; };
    float*          H    = (float*)(w + alloc((size_t)n * 256 * 4));
    unsigned short* X2h  = (unsigned short*)(w + alloc((size_t)n * 256 * 2));
    unsigned short* X2l  = (unsigned short*)(w + alloc((size_t)n * 256 * 2));
    // bufA: G pair (n*128*2 each) lives until gemm1; X3 pair (n*256*2 each) written after.
    char*           bufA = w + alloc((size_t)n * 256 * 4);
    unsigned short* Gh   = (unsigned short*)bufA;
    unsigned short* Gl   = Gh + (size_t)n * 128;
    unsigned short* X3h  = (unsigned short*)bufA;
    unsigned short* X3l  = X3h + (size_t)n * 256;
    unsigned short* Wt1h = (unsigned short*)(w + alloc(256 * 128 * 2));
    unsigned short* Wt1l = (unsigned short*)(w + alloc(256 * 128 * 2));
    unsigned short* Wt2h = (unsigned short*)(w + alloc(256 * 256 * 2));
    unsigned short* Wt2l = (unsigned short*)(w + alloc(256 * 256 * 2));
    unsigned short* Wt3h = (unsigned short*)(w + alloc(128 * 256 * 2));
    unsigned short* Wt3l = (unsigned short*)(w + alloc(128 * 256 * 2));
    float* bsb   = (float*)(w + alloc((size_t)n * 4));
    int*   scnt  = (int*)  (w + alloc((size_t)n * 4 * 3));
    int*   rcnt  = scnt + n;
    int*   cursor= scnt + 2 * n;
    int*   tmp   = (int*)  (w + alloc((size_t)n * 4));
    int*   off   = (int*)  (w + alloc((size_t)(n + 1) * 4));
    int*   bsum  = (int*)  (w + alloc(64 * 4));
    int*   esrc  = (int*)  (w + alloc((size_t)e * 4));
    float* snorm = (float*)(w + alloc((size_t)n * 4));
    float* rnorm = (float*)(w + alloc((size_t)n * 4));

    hipMemsetAsync(scnt, 0, (size_t)n * 4 * 3, stream);

    int eb = (e + 255) / 256;
    count_kernel<<<eb, 256, 0, stream>>>(snd, rcv, scnt, rcnt, e);
    int nb = (n + 1023) / 1024;
    scan_block_kernel<<<nb, 1024, 0, stream>>>(rcnt, tmp, bsum, n);
    scan_tops_kernel<<<1, 64, 0, stream>>>(bsum, nb);
    finalize_kernel<<<(n + 255) / 256, 256, 0, stream>>>(tmp, bsum, rcnt, scnt, off, rnorm, snorm, n);
    fill_kernel<<<eb, 256, 0, stream>>>(snd, rcv, off, cursor, esrc, e);

    wsplit_kernel<<<(128 * 256 + 255) / 256, 256, 0, stream>>>(W1, Wt1h, Wt1l, 128, 256);
    wsplit_kernel<<<(256 * 256 + 255) / 256, 256, 0, stream>>>(W2, Wt2h, Wt2l, 256, 256);
    wsplit_kernel<<<(256 * 128 + 255) / 256, 256, 0, stream>>>(W3, Wt3h, Wt3l, 256, 128);

    int gb = (n + 127) / 128;

    // L1
    gather1_kernel<<<((size_t)n * 32 + 255) / 256, 256, 0, stream>>>(nodes, off, esrc, snorm, rnorm, Gh, Gl, bsb, n);
    mfma_gemm<128, 256, true><<<dim3(gb, 2), 256, 0, stream>>>(Gh, Gl, Wt1h, Wt1l, b1, rnorm, bsb,
                                                               (float*)nullptr, X2h, X2l, n);
    // L2
    mfma_gemm<256, 256, false><<<dim3(gb, 2), 256, 0, stream>>>(X2h, X2l, Wt2h, Wt2l, b2, snorm, snorm,
                                                                H, (unsigned short*)nullptr, (unsigned short*)nullptr, n);
    gather2_kernel<<<((size_t)n * 64 + 255) / 256, 256, 0, stream>>>(H, off, esrc, rnorm, X3h, X3l, n);
    // L3
    mfma_gemm<256, 128, false><<<dim3(gb, 1), 256, 0, stream>>>(X3h, X3l, Wt3h, Wt3l, b3, snorm, snorm,
                                                                H, (unsigned short*)nullptr, (unsigned short*)nullptr, n);
    gather3_kernel<<<((size_t)n * 32 + 255) / 256, 256, 0, stream>>>(H, off, esrc, rnorm, out, n);
}

// Round 3
// 437.662 us; speedup vs baseline: 1.4057x; 1.0338x over previous
//
#include <hip/hip_runtime.h>

// GCN 3-layer, N=50000, E=800000, fp32 in/out.
// Pipeline:
//   CSR build (count -> scan -> fill)
//   L1: tiled gather(nodes*snorm, +sum snorm) -> bf16 split G ; MFMA-GEMM 128->256 (bf16x3) -> bf16 split X2
//   L2: MFMA-GEMM 256->256 -> fp32 H ; tiled gather -> relu(*rnorm) -> bf16 split X3
//   L3: MFMA-GEMM 256->128 -> fp32 H ; tiled gather -> relu(*rnorm) -> out
// Gathers are column-tiled (64 floats per blockIdx.y tile) so the random-row
// working set is 12.8MB (L2/L3-resident) instead of 51MB.

typedef __attribute__((ext_vector_type(8))) short short8;
typedef __attribute__((ext_vector_type(4))) float f32x4;

static __device__ __forceinline__ float reluf(float x){ return x > 0.f ? x : 0.f; }

static __device__ __forceinline__ unsigned short bf16_rn(float v){
    unsigned u = __float_as_uint(v);
    unsigned r = u + 0x7FFFu + ((u >> 16) & 1u);
    return (unsigned short)(r >> 16);
}
static __device__ __forceinline__ void split2(float v, unsigned short& h, unsigned short& l){
    unsigned short hh = bf16_rn(v);
    float hf = __uint_as_float(((unsigned)hh) << 16);
    h = hh;
    l = bf16_rn(v - hf);
}

static __device__ __forceinline__ void gload_lds16(const void* g, void* lds){
    __builtin_amdgcn_global_load_lds((const __attribute__((address_space(1))) unsigned int*)g,
                                     (__attribute__((address_space(3))) unsigned int*)lds, 16, 0, 0);
}

// ---------------- preprocessing (CSR build) ----------------

__global__ void count_kernel(const int* __restrict__ snd, const int* __restrict__ rcv,
                             int* __restrict__ scnt, int* __restrict__ rcnt, int e)
{
    int i = blockIdx.x * blockDim.x + threadIdx.x;
    if (i < e) {
        atomicAdd(&scnt[snd[i]], 1);
        atomicAdd(&rcnt[rcv[i]], 1);
    }
}

__global__ void scan_block_kernel(const int* __restrict__ cnt, int* __restrict__ tmp,
                                  int* __restrict__ bsum, int n)
{
    __shared__ int s[1024];
    int i = blockIdx.x * 1024 + threadIdx.x;
    int v = (i < n) ? cnt[i] : 0;
    s[threadIdx.x] = v;
    __syncthreads();
    for (int d = 1; d < 1024; d <<= 1) {
        int t = (threadIdx.x >= (unsigned)d) ? s[threadIdx.x - d] : 0;
        __syncthreads();
        s[threadIdx.x] += t;
        __syncthreads();
    }
    if (i < n) tmp[i] = s[threadIdx.x];
    if (threadIdx.x == 1023) bsum[blockIdx.x] = s[1023];
}

__global__ void scan_tops_kernel(int* bsum, int nb)
{
    __shared__ int s[64];
    int v = ((int)threadIdx.x < nb) ? bsum[threadIdx.x] : 0;
    s[threadIdx.x] = v;
    __syncthreads();
    for (int d = 1; d < 64; d <<= 1) {
        int t = (threadIdx.x >= (unsigned)d) ? s[threadIdx.x - d] : 0;
        __syncthreads();
        s[threadIdx.x] += t;
        __syncthreads();
    }
    if ((int)threadIdx.x < nb) bsum[threadIdx.x] = s[threadIdx.x] - v;  // exclusive
}

__global__ void finalize_kernel(const int* __restrict__ tmp, const int* __restrict__ bsum,
                                const int* __restrict__ rcnt, const int* __restrict__ scnt,
                                int* __restrict__ off, float* __restrict__ rnorm,
                                float* __restrict__ snorm, int n)
{
    int i = blockIdx.x * blockDim.x + threadIdx.x;
    if (i >= n) return;
    off[i + 1] = tmp[i] + bsum[i >> 10];
    if (i == 0) off[0] = 0;
    rnorm[i] = rsqrtf(fmaxf((float)rcnt[i], 1.0f));
    snorm[i] = rsqrtf(fmaxf((float)scnt[i], 1.0f));
}

__global__ void fill_kernel(const int* __restrict__ snd, const int* __restrict__ rcv,
                            const int* __restrict__ off, int* __restrict__ cursor,
                            int* __restrict__ esrc, int e)
{
    int i = blockIdx.x * blockDim.x + threadIdx.x;
    if (i < e) {
        int r = rcv[i];
        int p = off[r] + atomicAdd(&cursor[r], 1);
        esrc[p] = snd[i];
    }
}

// ---------------- weight split + transpose ----------------
__global__ void wsplit_kernel(const float* __restrict__ W, unsigned short* __restrict__ Th,
                              unsigned short* __restrict__ Tl, int K, int N)
{
    int i = blockIdx.x * 256 + threadIdx.x;
    if (i >= K * N) return;
    int k = i / N, c = i % N;
    unsigned short h, l;
    split2(W[i], h, l);
    Th[c * K + k] = h;
    Tl[c * K + k] = l;
}

// ---------------- MFMA GEMM (bf16x3 split fp32 emulation) ----------------
template<int K, int NOUT, bool RELU_SPLIT>
__global__ __launch_bounds__(256)
void mfma_gemm(const unsigned short* __restrict__ Ah_g, const unsigned short* __restrict__ Al_g,
               const unsigned short* __restrict__ Bh_g, const unsigned short* __restrict__ Bl_g,
               const float* __restrict__ bias, const float* __restrict__ rs,
               const float* __restrict__ bs, float* __restrict__ Hout,
               unsigned short* __restrict__ Oh, unsigned short* __restrict__ Ol, int n)
{
    __shared__ unsigned short smem[4 * 128 * 32];
    unsigned short* Ah = smem;
    unsigned short* Al = smem + 4096;
    unsigned short* Bh = smem + 8192;
    unsigned short* Bl = smem + 12288;

    const int tid = threadIdx.x;
    const int wid = tid >> 6, lane = tid & 63;
    const int wr = (wid >> 1) * 64, wc = (wid & 1) * 64;
    const int r0 = blockIdx.x * 128, c0 = blockIdx.y * 128;

    f32x4 acc[4][4];
#pragma unroll
    for (int m = 0; m < 4; ++m)
#pragma unroll
        for (int q = 0; q < 4; ++q) acc[m][q] = (f32x4){0.f, 0.f, 0.f, 0.f};

    const int ks = lane >> 4, lr = lane & 15;

    for (int k0 = 0; k0 < K; k0 += 32) {
#pragma unroll
        for (int c = 0; c < 2; ++c) {
            int i = tid + c * 256;
            int row = i >> 2, p = i & 3;
            int g = p ^ ((row >> 1) & 3);
            int ar = r0 + row; if (ar >= n) ar = n - 1;
            size_t aoff = (size_t)ar * K + k0 + g * 8;
            size_t boff = (size_t)(c0 + row) * K + k0 + g * 8;
            gload_lds16(Ah_g + aoff, Ah + i * 8);
            gload_lds16(Al_g + aoff, Al + i * 8);
            gload_lds16(Bh_g + boff, Bh + i * 8);
            gload_lds16(Bl_g + boff, Bl + i * 8);
        }
        __syncthreads();

        short8 a_h[4], a_l[4], b_h[4], b_l[4];
#pragma unroll
        for (int m = 0; m < 4; ++m) {
            int r = wr + m * 16 + lr;
            int slot = ks ^ ((r >> 1) & 3);
            a_h[m] = *(const short8*)(Ah + r * 32 + slot * 8);
            a_l[m] = *(const short8*)(Al + r * 32 + slot * 8);
        }
#pragma unroll
        for (int q = 0; q < 4; ++q) {
            int r = wc + q * 16 + lr;
            int slot = ks ^ ((r >> 1) & 3);
            b_h[q] = *(const short8*)(Bh + r * 32 + slot * 8);
            b_l[q] = *(const short8*)(Bl + r * 32 + slot * 8);
        }
#pragma unroll
        for (int m = 0; m < 4; ++m)
#pragma unroll
            for (int q = 0; q < 4; ++q) {
                acc[m][q] = __builtin_amdgcn_mfma_f32_16x16x32_bf16(a_h[m], b_h[q], acc[m][q], 0, 0, 0);
                acc[m][q] = __builtin_amdgcn_mfma_f32_16x16x32_bf16(a_h[m], b_l[q], acc[m][q], 0, 0, 0);
                acc[m][q] = __builtin_amdgcn_mfma_f32_16x16x32_bf16(a_l[m], b_h[q], acc[m][q], 0, 0, 0);
            }
        __syncthreads();
    }

    const int lq = lane >> 4;
#pragma unroll
    for (int m = 0; m < 4; ++m) {
#pragma unroll
        for (int j = 0; j < 4; ++j) {
            int r = r0 + wr + m * 16 + lq * 4 + j;
            if (r < n) {
                float rsv = rs[r], bsv = bs[r];
#pragma unroll
                for (int q = 0; q < 4; ++q) {
                    int cg = c0 + wc + q * 16 + lr;
                    float v = acc[m][q][j] * rsv + bias[cg] * bsv;
                    if (RELU_SPLIT) {
                        v = reluf(v);
                        unsigned short h, l;
                        split2(v, h, l);
                        Oh[(size_t)r * NOUT + cg] = h;
                        Ol[(size_t)r * NOUT + cg] = l;
                    } else {
                        Hout[(size_t)r * NOUT + cg] = v;
                    }
                }
            }
        }
    }
}

// ---------------- column-tiled gathers ----------------
// 32 lanes per node, float2 per lane => 64-float tile per blockIdx.y.
// Working set per tile pass = n*256B = 12.8MB (L2/L3 resident).

// L1: G = sum nodes[s]*snorm[s] (bf16 pair out); bs = (sum snorm)*rnorm (tile0 only).
__global__ __launch_bounds__(256)
void gather1_t(const float* __restrict__ nodes, const int* __restrict__ off,
               const int* __restrict__ esrc, const float* __restrict__ snorm,
               const float* __restrict__ rnorm,
               unsigned short* __restrict__ Gh, unsigned short* __restrict__ Gl,
               float* __restrict__ bs, int n)
{
    int g = blockIdx.x * 256 + threadIdx.x;
    int node = g >> 5, lane = g & 31;
    if (node >= n) return;
    int col = blockIdx.y * 64 + lane * 2;
    const float* Nc = nodes + col;
    int e0 = off[node], e1 = off[node + 1];
    float ax = 0, ay = 0, gs = 0;
    int e = e0;
    for (; e + 4 <= e1; e += 4) {
        int s0 = esrc[e], s1 = esrc[e + 1], s2 = esrc[e + 2], s3 = esrc[e + 3];
        float n0 = snorm[s0], n1 = snorm[s1], n2 = snorm[s2], n3 = snorm[s3];
        float2 v0 = *(const float2*)(Nc + (size_t)s0 * 128);
        float2 v1 = *(const float2*)(Nc + (size_t)s1 * 128);
        float2 v2 = *(const float2*)(Nc + (size_t)s2 * 128);
        float2 v3 = *(const float2*)(Nc + (size_t)s3 * 128);
        ax += v0.x * n0 + v1.x * n1 + v2.x * n2 + v3.x * n3;
        ay += v0.y * n0 + v1.y * n1 + v2.y * n2 + v3.y * n3;
        gs += n0 + n1 + n2 + n3;
    }
    for (; e < e1; ++e) {
        int s = esrc[e];
        float ns = snorm[s];
        float2 v = *(const float2*)(Nc + (size_t)s * 128);
        ax += v.x * ns; ay += v.y * ns;
        gs += ns;
    }
    unsigned short hx, lx, hy, ly;
    split2(ax, hx, lx); split2(ay, hy, ly);
    size_t o = (size_t)node * 128 + col;
    *(ushort2*)(Gh + o) = make_ushort2(hx, hy);
    *(ushort2*)(Gl + o) = make_ushort2(lx, ly);
    if (blockIdx.y == 0 && lane == 0) bs[node] = gs * rnorm[node];
}

// L2: X3 = relu(rnorm * sum H[s]) (bf16 pair out), F=256.
__global__ __launch_bounds__(256)
void gather2_t(const float* __restrict__ H, const int* __restrict__ off,
               const int* __restrict__ esrc, const float* __restrict__ rnorm,
               unsigned short* __restrict__ Oh, unsigned short* __restrict__ Ol, int n)
{
    int g = blockIdx.x * 256 + threadIdx.x;
    int node = g >> 5, lane = g & 31;
    if (node >= n) return;
    int col = blockIdx.y * 64 + lane * 2;
    const float* Hc = H + col;
    int e0 = off[node], e1 = off[node + 1];
    float ax = 0, ay = 0;
    int e = e0;
    for (; e + 4 <= e1; e += 4) {
        int s0 = esrc[e], s1 = esrc[e + 1], s2 = esrc[e + 2], s3 = esrc[e + 3];
        float2 v0 = *(const float2*)(Hc + (size_t)s0 * 256);
        float2 v1 = *(const float2*)(Hc + (size_t)s1 * 256);
        float2 v2 = *(const float2*)(Hc + (size_t)s2 * 256);
        float2 v3 = *(const float2*)(Hc + (size_t)s3 * 256);
        ax += v0.x + v1.x + v2.x + v3.x;
        ay += v0.y + v1.y + v2.y + v3.y;
    }
    for (; e < e1; ++e) {
        int s = esrc[e];
        float2 v = *(const float2*)(Hc + (size_t)s * 256);
        ax += v.x; ay += v.y;
    }
    float rn = rnorm[node];
    float vx = reluf(ax * rn), vy = reluf(ay * rn);
    unsigned short hx, lx, hy, ly;
    split2(vx, hx, lx); split2(vy, hy, ly);
    size_t o = (size_t)node * 256 + col;
    *(ushort2*)(Oh + o) = make_ushort2(hx, hy);
    *(ushort2*)(Ol + o) = make_ushort2(lx, ly);
}

// L3: out = relu(rnorm * sum H[s]) fp32, F=128.
__global__ __launch_bounds__(256)
void gather3_t(const float* __restrict__ H, const int* __restrict__ off,
               const int* __restrict__ esrc, const float* __restrict__ rnorm,
               float* __restrict__ out, int n)
{
    int g = blockIdx.x * 256 + threadIdx.x;
    int node = g >> 5, lane = g & 31;
    if (node >= n) return;
    int col = blockIdx.y * 64 + lane * 2;
    const float* Hc = H + col;
    int e0 = off[node], e1 = off[node + 1];
    float ax = 0, ay = 0;
    int e = e0;
    for (; e + 4 <= e1; e += 4) {
        int s0 = esrc[e], s1 = esrc[e + 1], s2 = esrc[e + 2], s3 = esrc[e + 3];
        float2 v0 = *(const float2*)(Hc + (size_t)s0 * 128);
        float2 v1 = *(const float2*)(Hc + (size_t)s1 * 128);
        float2 v2 = *(const float2*)(Hc + (size_t)s2 * 128);
        float2 v3 = *(const float2*)(Hc + (size_t)s3 * 128);
        ax += v0.x + v1.x + v2.x + v3.x;
        ay += v0.y + v1.y + v2.y + v3.y;
    }
    for (; e < e1; ++e) {
        int s = esrc[e];
        float2 v = *(const float2*)(Hc + (size_t)s * 128);
        ax += v.x; ay += v.y;
    }
    float rn = rnorm[node];
    float2 o = { reluf(ax * rn), reluf(ay * rn) };
    *(float2*)(out + (size_t)node * 128 + col) = o;
}

// ---------------- launch ----------------

extern "C" void kernel_launch(void* const* d_in, const int* in_sizes, int n_in,
                              void* d_out, int out_size, void* d_ws, size_t ws_size,
                              hipStream_t stream)
{
    const float* nodes = (const float*)d_in[0];
    const int*   snd   = (const int*)d_in[1];
    const int*   rcv   = (const int*)d_in[2];
    const float* W1    = (const float*)d_in[3];
    const float* b1    = (const float*)d_in[4];
    const float* W2    = (const float*)d_in[5];
    const float* b2    = (const float*)d_in[6];
    const float* W3    = (const float*)d_in[7];
    const float* b3    = (const float*)d_in[8];
    const int n = in_sizes[0] / 128;
    const int e = in_sizes[1];
    float* out = (float*)d_out;

    char* w = (char*)d_ws;
    size_t o = 0;
    auto alloc = [&](size_t b){ size_t p = o; o += (b + 255) & ~(size_t)255; return p; };
    float*          H    = (float*)(w + alloc((size_t)n * 256 * 4));
    unsigned short* X2h  = (unsigned short*)(w + alloc((size_t)n * 256 * 2));
    unsigned short* X2l  = (unsigned short*)(w + alloc((size_t)n * 256 * 2));
    char*           bufA = w + alloc((size_t)n * 256 * 4);
    unsigned short* Gh   = (unsigned short*)bufA;
    unsigned short* Gl   = Gh + (size_t)n * 128;
    unsigned short* X3h  = (unsigned short*)bufA;
    unsigned short* X3l  = X3h + (size_t)n * 256;
    unsigned short* Wt1h = (unsigned short*)(w + alloc(256 * 128 * 2));
    unsigned short* Wt1l = (unsigned short*)(w + alloc(256 * 128 * 2));
    unsigned short* Wt2h = (unsigned short*)(w + alloc(256 * 256 * 2));
    unsigned short* Wt2l = (unsigned short*)(w + alloc(256 * 256 * 2));
    unsigned short* Wt3h = (unsigned short*)(w + alloc(128 * 256 * 2));
    unsigned short* Wt3l = (unsigned short*)(w + alloc(128 * 256 * 2));
    float* bsb   = (float*)(w + alloc((size_t)n * 4));
    int*   scnt  = (int*)  (w + alloc((size_t)n * 4 * 3));
    int*   rcnt  = scnt + n;
    int*   cursor= scnt + 2 * n;
    int*   tmp   = (int*)  (w + alloc((size_t)n * 4));
    int*   off   = (int*)  (w + alloc((size_t)(n + 1) * 4));
    int*   bsum  = (int*)  (w + alloc(64 * 4));
    int*   esrc  = (int*)  (w + alloc((size_t)e * 4));
    float* snorm = (float*)(w + alloc((size_t)n * 4));
    float* rnorm = (float*)(w + alloc((size_t)n * 4));

    hipMemsetAsync(scnt, 0, (size_t)n * 4 * 3, stream);

    int eb = (e + 255) / 256;
    count_kernel<<<eb, 256, 0, stream>>>(snd, rcv, scnt, rcnt, e);
    int nb = (n + 1023) / 1024;
    scan_block_kernel<<<nb, 1024, 0, stream>>>(rcnt, tmp, bsum, n);
    scan_tops_kernel<<<1, 64, 0, stream>>>(bsum, nb);
    finalize_kernel<<<(n + 255) / 256, 256, 0, stream>>>(tmp, bsum, rcnt, scnt, off, rnorm, snorm, n);
    fill_kernel<<<eb, 256, 0, stream>>>(snd, rcv, off, cursor, esrc, e);

    wsplit_kernel<<<(128 * 256 + 255) / 256, 256, 0, stream>>>(W1, Wt1h, Wt1l, 128, 256);
    wsplit_kernel<<<(256 * 256 + 255) / 256, 256, 0, stream>>>(W2, Wt2h, Wt2l, 256, 256);
    wsplit_kernel<<<(256 * 128 + 255) / 256, 256, 0, stream>>>(W3, Wt3h, Wt3l, 256, 128);

    int gb = (n + 127) / 128;
    int lb = ((size_t)n * 32 + 255) / 256;   // blocks per tile pass (32 lanes/node)

    // L1
    gather1_t<<<dim3(lb, 2), 256, 0, stream>>>(nodes, off, esrc, snorm, rnorm, Gh, Gl, bsb, n);
    mfma_gemm<128, 256, true><<<dim3(gb, 2), 256, 0, stream>>>(Gh, Gl, Wt1h, Wt1l, b1, rnorm, bsb,
                                                               (float*)nullptr, X2h, X2l, n);
    // L2
    mfma_gemm<256, 256, false><<<dim3(gb, 2), 256, 0, stream>>>(X2h, X2l, Wt2h, Wt2l, b2, snorm, snorm,
                                                                H, (unsigned short*)nullptr, (unsigned short*)nullptr, n);
    gather2_t<<<dim3(lb, 4), 256, 0, stream>>>(H, off, esrc, rnorm, X3h, X3l, n);
    // L3
    mfma_gemm<256, 128, false><<<dim3(gb, 1), 256, 0, stream>>>(X3h, X3l, Wt3h, Wt3l, b3, snorm, snorm,
                                                                H, (unsigned short*)nullptr, (unsigned short*)nullptr, n);
    gather3_t<<<dim3(lb, 2), 256, 0, stream>>>(H, off, esrc, rnorm, out, n);
}